// Round 1
// baseline (554.519 us; speedup 1.0000x reference)
//
#include <hip/hip_runtime.h>
#include <stdint.h>

typedef __attribute__((ext_vector_type(4))) float f32x4;
typedef __attribute__((ext_vector_type(8))) __bf16 bf16x8;
typedef __attribute__((ext_vector_type(4))) __bf16 bf16x4;

#define MFMA16(a, b, c) __builtin_amdgcn_mfma_f32_16x16x32_bf16(a, b, c, 0, 0, 0)

#define B_ 4
#define S_ 2048
#define D_ 1024
#define H_ 16
#define NEG_ -1e10f

__device__ __forceinline__ void glds16(const void* gsrc, void* ldst) {
  __builtin_amdgcn_global_load_lds(
      (__attribute__((address_space(1))) void*)(gsrc),
      (__attribute__((address_space(3))) void*)(ldst),
      16, 0, 0);
}

// ---------------- fp32 -> bf16 convert ----------------
__global__ __launch_bounds__(256) void cvt_f32_bf16(const float* __restrict__ in,
                                                    __bf16* __restrict__ out, int n) {
  int i = (blockIdx.x * 256 + threadIdx.x) * 4;
  if (i < n) {
    float4 v = *(const float4*)(in + i);
    bf16x4 o;
    o.x = (__bf16)v.x; o.y = (__bf16)v.y; o.z = (__bf16)v.z; o.w = (__bf16)v.w;
    *(bf16x4*)(out + i) = o;
  }
}

// ---------------- mask pack: bits + per-tile all-ones flags ----------------
__global__ __launch_bounds__(256) void mask_pack(const int* __restrict__ mask,
                                                 uint32_t* __restrict__ bits,
                                                 int* __restrict__ flags) {
  // grid: (tt=16, st=16, b=4); tile 128x128
  int tt = blockIdx.x, st = blockIdx.y, b = blockIdx.z;
  int tid = threadIdx.x, w = tid >> 6, lane = tid & 63;
  __shared__ int andred;
  if (tid == 0) andred = 1;
  __syncthreads();
  unsigned long long all1 = ~0ull;
  for (int rr = 0; rr < 32; rr++) {
    int srow = st * 128 + w * 32 + rr;
    #pragma unroll
    for (int half = 0; half < 2; half++) {
      int c = tt * 128 + half * 64 + lane;
      int m = mask[((size_t)b * S_ + srow) * S_ + c];
      unsigned long long bal = __ballot(m != 0);
      all1 &= bal;
      if (lane == 0) {
        uint32_t* dst = &bits[((size_t)b * S_ + srow) * 64 + tt * 4 + half * 2];
        dst[0] = (uint32_t)bal;
        dst[1] = (uint32_t)(bal >> 32);
      }
    }
  }
  if (all1 != ~0ull) atomicAnd(&andred, 0);
  __syncthreads();
  if (tid == 0) flags[(b * 16 + st) * 16 + tt] = andred;
}

// ---------------- GEMM: C[m][n] = sum_k A[m][k] * W[n][k], K=N=1024 ----------------
// MODE 0: bf16 out in [B,H,S,64] layout (z selects q/k/v; q scaled by 0.125)
// MODE 1: f32 out row-major [M,1024]
template <int MODE>
__global__ __launch_bounds__(256, 2) void gemm_bt(
    const __bf16* __restrict__ A0, const __bf16* __restrict__ A1, const __bf16* __restrict__ A2,
    const __bf16* __restrict__ W0, const __bf16* __restrict__ W1, const __bf16* __restrict__ W2,
    void* O0, void* O1, void* O2) {
  const int K = 1024;
  const __bf16* A; const __bf16* W; void* O; float scale = 1.0f;
  if (MODE == 0) {
    if (blockIdx.z == 0)      { A = A0; W = W0; O = O0; scale = 0.125f; }
    else if (blockIdx.z == 1) { A = A1; W = W1; O = O1; }
    else                      { A = A2; W = W2; O = O2; }
  } else { A = A0; W = W0; O = O0; }

  __shared__ __align__(16) __bf16 As[128 * 32];
  __shared__ __align__(16) __bf16 Bs[128 * 32];
  int tid = threadIdx.x, lane = tid & 63, w = tid >> 6;
  int wm = w >> 1, wn = w & 1;
  int g = lane >> 4, l15 = lane & 15;
  f32x4 acc[4][4] = {};
  const __bf16* Ablk = A + (size_t)(blockIdx.y * 128) * K;
  const __bf16* Wblk = W + (size_t)(blockIdx.x * 128) * K;
  int srow = tid >> 2;          // 0..63
  int scol = (tid & 3) * 8;

  for (int kt = 0; kt < K; kt += 32) {
    __syncthreads();
    glds16(Ablk + (size_t)srow * K + kt + scol,        (char*)As + tid * 16);
    glds16(Ablk + (size_t)(srow + 64) * K + kt + scol, (char*)As + 4096 + tid * 16);
    glds16(Wblk + (size_t)srow * K + kt + scol,        (char*)Bs + tid * 16);
    glds16(Wblk + (size_t)(srow + 64) * K + kt + scol, (char*)Bs + 4096 + tid * 16);
    __syncthreads();
    bf16x8 af[4], bfr[4];
    #pragma unroll
    for (int i = 0; i < 4; i++)
      af[i] = *(const bf16x8*)((const char*)As + (wm * 64 + i * 16 + l15) * 64 + g * 16);
    #pragma unroll
    for (int j = 0; j < 4; j++)
      bfr[j] = *(const bf16x8*)((const char*)Bs + (wn * 64 + j * 16 + l15) * 64 + g * 16);
    #pragma unroll
    for (int i = 0; i < 4; i++)
      #pragma unroll
      for (int j = 0; j < 4; j++)
        acc[i][j] = MFMA16(af[i], bfr[j], acc[i][j]);
  }

  #pragma unroll
  for (int i = 0; i < 4; i++)
    #pragma unroll
    for (int j = 0; j < 4; j++)
      #pragma unroll
      for (int r = 0; r < 4; r++) {
        int m = blockIdx.y * 128 + wm * 64 + i * 16 + g * 4 + r;
        int n = blockIdx.x * 128 + wn * 64 + j * 16 + l15;
        float v = acc[i][j][r];
        if (MODE == 0) {
          size_t idx = (((size_t)(m >> 11) * 16 + (n >> 6)) * 2048 + (m & 2047)) * 64 + (n & 63);
          ((__bf16*)O)[idx] = (__bf16)(v * scale);
        } else {
          ((float*)O)[(size_t)m * 1024 + n] = v;
        }
      }
}

// ---------------- V transpose: [B,H,S,64] -> [B,H,64,S] ----------------
__global__ __launch_bounds__(256) void vtrans(const __bf16* __restrict__ vin,
                                              __bf16* __restrict__ vout) {
  // grid: (S/64=32, BH=64); tile 64 s x 64 dv
  int st = blockIdx.x, bh = blockIdx.y;
  __shared__ __align__(16) __bf16 t[64 * 72];
  int tid = threadIdx.x;
  const __bf16* src = vin + ((size_t)bh * S_ + st * 64) * 64;
  #pragma unroll
  for (int r = 0; r < 2; r++) {
    int e = r * 2048 + tid * 8;
    int s = e >> 6, dv = e & 63;
    bf16x8 v = *(const bf16x8*)(src + e);
    *(bf16x8*)(&t[s * 72 + dv]) = v;
  }
  __syncthreads();
  #pragma unroll
  for (int r = 0; r < 2; r++) {
    int e = r * 2048 + tid * 8;
    int dv = e >> 6, s0 = e & 63;
    bf16x8 o;
    #pragma unroll
    for (int k = 0; k < 8; k++) o[k] = t[(s0 + k) * 72 + dv];
    *(bf16x8*)(vout + ((size_t)bh * 64 + dv) * S_ + st * 64 + s0) = o;
  }
}

// ---------------- flash attention ----------------
__global__ __launch_bounds__(256, 2) void attn(
    const __bf16* __restrict__ qp, const __bf16* __restrict__ kp,
    const __bf16* __restrict__ vt, __bf16* __restrict__ aout,
    const uint32_t* __restrict__ bits, const int* __restrict__ flags) {
  // grid: (qt=16, bh=64)
  int qt = blockIdx.x, bh = blockIdx.y, b = bh >> 4, h = bh & 15;
  int tid = threadIdx.x, lane = tid & 63, w = tid >> 6;
  int g = lane >> 4, l15 = lane & 15;

  __shared__ __align__(16) char smem[67584];
  char* Klds = smem;              // [128][64] bf16 = 16384
  char* Vlds = smem + 16384;      // [64][128] bf16 = 16384
  char* PQ   = smem + 32768;      // Q [128][64] (init) then P: per wave [32][136] bf16

  const __bf16* Qg = qp + ((size_t)bh * S_ + qt * 128) * 64;
  const __bf16* Kg = kp + (size_t)bh * S_ * 64;
  const __bf16* Vg = vt + (size_t)bh * 64 * S_;

  // stage Q (contiguous 16 KB)
  #pragma unroll
  for (int r = 0; r < 4; r++)
    glds16((const char*)Qg + r * 4096 + tid * 16, PQ + r * 4096 + tid * 16);
  __syncthreads();
  bf16x8 qf[2][2];
  #pragma unroll
  for (int i = 0; i < 2; i++)
    #pragma unroll
    for (int kk = 0; kk < 2; kk++)
      qf[i][kk] = *(const bf16x8*)(PQ + (w * 32 + i * 16 + l15) * 128 + kk * 64 + g * 16);
  __syncthreads();  // everyone has Q frags; PQ region becomes P scratch

  char* Pl = PQ + w * 8704;  // this wave's P: [32][136] bf16

  f32x4 oacc[2][4] = {};
  float mst[2][4], lst[2][4];
  #pragma unroll
  for (int i = 0; i < 2; i++)
    #pragma unroll
    for (int r = 0; r < 4; r++) { mst[i][r] = -INFINITY; lst[i][r] = 0.f; }

  for (int kt = 0; kt < 16; kt++) {
    const char* Ksrc = (const char*)(Kg + (size_t)kt * 128 * 64);
    #pragma unroll
    for (int r = 0; r < 4; r++)
      glds16(Ksrc + r * 4096 + tid * 16, Klds + r * 4096 + tid * 16);
    #pragma unroll
    for (int r = 0; r < 4; r++) {
      int L = r * 4096 + tid * 16;
      int dv = L >> 8, seg = L & 255;
      glds16((const char*)(Vg + (size_t)dv * S_ + kt * 128) + seg, Vlds + L);
    }
    __syncthreads();

    // S = Q K^T (scale folded into q)
    f32x4 sacc[2][8] = {};
    #pragma unroll
    for (int j = 0; j < 8; j++) {
      bf16x8 b0 = *(const bf16x8*)(Klds + (j * 16 + l15) * 128 + g * 16);
      bf16x8 b1 = *(const bf16x8*)(Klds + (j * 16 + l15) * 128 + 64 + g * 16);
      #pragma unroll
      for (int i = 0; i < 2; i++) {
        sacc[i][j] = MFMA16(qf[i][0], b0, sacc[i][j]);
        sacc[i][j] = MFMA16(qf[i][1], b1, sacc[i][j]);
      }
    }

    int flag = flags[(b * 16 + qt) * 16 + kt];
    if (flag == 0) {  // slow path: exact mask application (not hit for all-ones mask)
      #pragma unroll
      for (int i = 0; i < 2; i++)
        #pragma unroll
        for (int j = 0; j < 8; j++)
          #pragma unroll
          for (int r = 0; r < 4; r++) {
            int srow = qt * 128 + w * 32 + i * 16 + g * 4 + r;
            int tcol = kt * 128 + j * 16 + l15;
            uint32_t word = bits[((size_t)b * S_ + srow) * 64 + (tcol >> 5)];
            if (!((word >> (tcol & 31)) & 1)) sacc[i][j][r] = NEG_;
          }
    }

    // online softmax per row; write P (bf16) to LDS
    #pragma unroll
    for (int i = 0; i < 2; i++) {
      #pragma unroll
      for (int r = 0; r < 4; r++) {
        float mx = sacc[i][0][r];
        #pragma unroll
        for (int j = 1; j < 8; j++) mx = fmaxf(mx, sacc[i][j][r]);
        #pragma unroll
        for (int off = 8; off; off >>= 1) mx = fmaxf(mx, __shfl_xor(mx, off));
        float mold = mst[i][r];
        float mnew = fmaxf(mold, mx);
        mst[i][r] = mnew;
        float alpha = __expf(mold - mnew);
        float p[8], sum = 0.f;
        #pragma unroll
        for (int j = 0; j < 8; j++) { p[j] = __expf(sacc[i][j][r] - mnew); sum += p[j]; }
        #pragma unroll
        for (int off = 8; off; off >>= 1) sum += __shfl_xor(sum, off);
        lst[i][r] = lst[i][r] * alpha + sum;
        #pragma unroll
        for (int jt = 0; jt < 4; jt++) oacc[i][jt][r] *= alpha;
        __bf16* prow = (__bf16*)Pl + (i * 16 + g * 4 + r) * 136;
        #pragma unroll
        for (int j = 0; j < 8; j++) prow[j * 16 + l15] = (__bf16)p[j];
      }
    }

    // O += P @ V
    #pragma unroll
    for (int kk = 0; kk < 4; kk++) {
      bf16x8 pf[2], vf[4];
      #pragma unroll
      for (int i = 0; i < 2; i++)
        pf[i] = *(const bf16x8*)(Pl + (i * 16 + l15) * 272 + kk * 64 + g * 16);
      #pragma unroll
      for (int jt = 0; jt < 4; jt++)
        vf[jt] = *(const bf16x8*)(Vlds + (jt * 16 + l15) * 256 + kk * 64 + g * 16);
      #pragma unroll
      for (int i = 0; i < 2; i++)
        #pragma unroll
        for (int jt = 0; jt < 4; jt++)
          oacc[i][jt] = MFMA16(pf[i], vf[jt], oacc[i][jt]);
    }
    __syncthreads();  // K/V consumed; safe to restage
  }

  // epilogue: O / l -> attn_out [B,S,H*64] bf16
  #pragma unroll
  for (int i = 0; i < 2; i++)
    #pragma unroll
    for (int r = 0; r < 4; r++) {
      float inv = 1.0f / lst[i][r];
      int srow = qt * 128 + w * 32 + i * 16 + g * 4 + r;
      #pragma unroll
      for (int jt = 0; jt < 4; jt++) {
        float v = oacc[i][jt][r] * inv;
        aout[((size_t)b * S_ + srow) * 1024 + h * 64 + jt * 16 + l15] = (__bf16)v;
      }
    }
}

// ---------------- launch ----------------
extern "C" void kernel_launch(void* const* d_in, const int* in_sizes, int n_in,
                              void* d_out, int out_size, void* d_ws, size_t ws_size,
                              hipStream_t stream) {
  const float* queries = (const float*)d_in[0];
  const float* keys    = (const float*)d_in[1];
  const float* values  = (const float*)d_in[2];
  const int*   mask    = (const int*)d_in[3];
  const float* Wq      = (const float*)d_in[4];
  const float* Wk      = (const float*)d_in[5];
  const float* Wv      = (const float*)d_in[6];
  const float* Wo      = (const float*)d_in[7];

  char* ws = (char*)d_ws;
  __bf16* Xq  = (__bf16*)(ws + 0);          // 16 MB, later reused as attn_out
  __bf16* Xk  = (__bf16*)(ws + 16777216);   // 16 MB, later reused as v_T
  __bf16* Xv  = (__bf16*)(ws + 33554432);   // 16 MB
  __bf16* Wqb = (__bf16*)(ws + 50331648);   // 2 MB
  __bf16* Wkb = (__bf16*)(ws + 52428800);
  __bf16* Wvb = (__bf16*)(ws + 54525952);
  __bf16* Wob = (__bf16*)(ws + 56623104);
  __bf16* qp  = (__bf16*)(ws + 58720256);   // 16 MB [B,H,S,64]
  __bf16* kp  = (__bf16*)(ws + 75497472);
  __bf16* vp  = (__bf16*)(ws + 92274688);
  uint32_t* bits = (uint32_t*)(ws + 109051904);  // 2 MB
  int* flags     = (int*)(ws + 111149056);       // 4 KB
  __bf16* vT   = Xk;  // alias: Xk dead after proj GEMM
  __bf16* aout = Xq;  // alias: Xq dead after proj GEMM

  const int NQ = B_ * S_ * D_;   // 8388608
  const int NW = H_ * 64 * D_;   // 1048576

  cvt_f32_bf16<<<NQ / 1024, 256, 0, stream>>>(queries, Xq, NQ);
  cvt_f32_bf16<<<NQ / 1024, 256, 0, stream>>>(keys,    Xk, NQ);
  cvt_f32_bf16<<<NQ / 1024, 256, 0, stream>>>(values,  Xv, NQ);
  cvt_f32_bf16<<<NW / 1024, 256, 0, stream>>>(Wq, Wqb, NW);
  cvt_f32_bf16<<<NW / 1024, 256, 0, stream>>>(Wk, Wkb, NW);
  cvt_f32_bf16<<<NW / 1024, 256, 0, stream>>>(Wv, Wvb, NW);
  cvt_f32_bf16<<<NW / 1024, 256, 0, stream>>>(Wo, Wob, NW);

  mask_pack<<<dim3(16, 16, 4), 256, 0, stream>>>(mask, bits, flags);

  gemm_bt<0><<<dim3(8, 64, 3), 256, 0, stream>>>(Xq, Xk, Xv, Wqb, Wkb, Wvb,
                                                 (void*)qp, (void*)kp, (void*)vp);

  vtrans<<<dim3(32, 64), 256, 0, stream>>>(vp, vT);

  attn<<<dim3(16, 64), 256, 0, stream>>>(qp, kp, vT, aout, bits, flags);

  gemm_bt<1><<<dim3(8, 64, 1), 256, 0, stream>>>(aout, nullptr, nullptr, Wob, nullptr, nullptr,
                                                 (void*)d_out, nullptr, nullptr);
}

// Round 2
// 486.998 us; speedup vs baseline: 1.1386x; 1.1386x over previous
//
#include <hip/hip_runtime.h>
#include <stdint.h>

typedef __attribute__((ext_vector_type(4))) float f32x4;
typedef __attribute__((ext_vector_type(8))) __bf16 bf16x8;
typedef __attribute__((ext_vector_type(4))) __bf16 bf16x4;

#define MFMA16(a, b, c) __builtin_amdgcn_mfma_f32_16x16x32_bf16(a, b, c, 0, 0, 0)

#define B_ 4
#define S_ 2048
#define D_ 1024
#define H_ 16
#define NEG_ -1e10f

__device__ __forceinline__ void glds16(const void* gsrc, void* ldst) {
  __builtin_amdgcn_global_load_lds(
      (__attribute__((address_space(1))) void*)(gsrc),
      (__attribute__((address_space(3))) void*)(ldst),
      16, 0, 0);
}

__device__ __forceinline__ uint32_t pack_bf16(float a, float b) {
  uint32_t ua = (uint32_t)__builtin_bit_cast(unsigned short, (__bf16)a);
  uint32_t ub = (uint32_t)__builtin_bit_cast(unsigned short, (__bf16)b);
  return ua | (ub << 16);
}

// ---------------- fp32 -> bf16 converts (fused) ----------------
__global__ __launch_bounds__(256) void cvt3(const float* __restrict__ a, const float* __restrict__ b,
                                            const float* __restrict__ c, __bf16* __restrict__ oa,
                                            __bf16* __restrict__ ob, __bf16* __restrict__ oc) {
  const float* in; __bf16* out;
  if (blockIdx.z == 0) { in = a; out = oa; }
  else if (blockIdx.z == 1) { in = b; out = ob; }
  else { in = c; out = oc; }
  int i = (blockIdx.x * 256 + threadIdx.x) * 4;
  float4 v = *(const float4*)(in + i);
  bf16x4 o;
  o.x = (__bf16)v.x; o.y = (__bf16)v.y; o.z = (__bf16)v.z; o.w = (__bf16)v.w;
  *(bf16x4*)(out + i) = o;
}

__global__ __launch_bounds__(256) void cvt4(const float* __restrict__ a, const float* __restrict__ b,
                                            const float* __restrict__ c, const float* __restrict__ d,
                                            __bf16* __restrict__ oa, __bf16* __restrict__ ob,
                                            __bf16* __restrict__ oc, __bf16* __restrict__ od) {
  const float* in; __bf16* out;
  if (blockIdx.z == 0) { in = a; out = oa; }
  else if (blockIdx.z == 1) { in = b; out = ob; }
  else if (blockIdx.z == 2) { in = c; out = oc; }
  else { in = d; out = od; }
  int i = (blockIdx.x * 256 + threadIdx.x) * 4;
  float4 v = *(const float4*)(in + i);
  bf16x4 o;
  o.x = (__bf16)v.x; o.y = (__bf16)v.y; o.z = (__bf16)v.z; o.w = (__bf16)v.w;
  *(bf16x4*)(out + i) = o;
}

// ---------------- mask pack: bits + per-tile all-ones flags ----------------
__global__ __launch_bounds__(256) void mask_pack(const int* __restrict__ mask,
                                                 uint32_t* __restrict__ bits,
                                                 int* __restrict__ flags) {
  int tt = blockIdx.x, st = blockIdx.y, b = blockIdx.z;
  int tid = threadIdx.x, w = tid >> 6, lane = tid & 63;
  __shared__ int andred;
  if (tid == 0) andred = 1;
  __syncthreads();
  unsigned long long all1 = ~0ull;
  for (int rr = 0; rr < 32; rr++) {
    int srow = st * 128 + w * 32 + rr;
    #pragma unroll
    for (int half = 0; half < 2; half++) {
      int c = tt * 128 + half * 64 + lane;
      int m = mask[((size_t)b * S_ + srow) * S_ + c];
      unsigned long long bal = __ballot(m != 0);
      all1 &= bal;
      if (lane == 0) {
        uint32_t* dst = &bits[((size_t)b * S_ + srow) * 64 + tt * 4 + half * 2];
        dst[0] = (uint32_t)bal;
        dst[1] = (uint32_t)(bal >> 32);
      }
    }
  }
  if (all1 != ~0ull) atomicAnd(&andred, 0);
  __syncthreads();
  if (tid == 0) flags[(b * 16 + st) * 16 + tt] = andred;
}

// ---------------- GEMM: C[m][n] = sum_k A[m][k] * W[n][k], K=N=1024, BK=64 swizzled ----------------
// MODE 0: bf16 out; z=0 q ([B,H,S,64], *0.125), z=1 k ([B,H,S,64]), z=2 v transposed ([B,H,64,S])
// MODE 1: f32 out row-major [M,1024]
template <int MODE>
__global__ __launch_bounds__(256, 2) void gemm_bt(
    const __bf16* __restrict__ A0, const __bf16* __restrict__ A1, const __bf16* __restrict__ A2,
    const __bf16* __restrict__ W0, const __bf16* __restrict__ W1, const __bf16* __restrict__ W2,
    void* O0, void* O1, void* O2) {
  const int K = 1024;
  const __bf16* A; const __bf16* W; void* O; float scale = 1.0f;
  if (MODE == 0) {
    if (blockIdx.z == 0)      { A = A0; W = W0; O = O0; scale = 0.125f; }
    else if (blockIdx.z == 1) { A = A1; W = W1; O = O1; }
    else                      { A = A2; W = W2; O = O2; }
  } else { A = A0; W = W0; O = O0; }

  __shared__ __align__(16) __bf16 As[128 * 64];
  __shared__ __align__(16) __bf16 Bs[128 * 64];
  int tid = threadIdx.x, lane = tid & 63, w = tid >> 6;
  int wm = w >> 1, wn = w & 1;
  int g = lane >> 4, l15 = lane & 15;
  f32x4 acc[4][4] = {};
  const __bf16* Ablk = A + (size_t)(blockIdx.y * 128) * K;
  const __bf16* Wblk = W + (size_t)(blockIdx.x * 128) * K;

  for (int kt = 0; kt < K; kt += 64) {
    __syncthreads();
    #pragma unroll
    for (int r = 0; r < 4; r++) {
      int C = r * 256 + tid;
      int row = C >> 3, c = C & 7;
      int c0 = c ^ (row & 7);
      glds16(Ablk + (size_t)row * K + kt + c0 * 8, (char*)As + C * 16);
      glds16(Wblk + (size_t)row * K + kt + c0 * 8, (char*)Bs + C * 16);
    }
    __syncthreads();
    #pragma unroll
    for (int kkq = 0; kkq < 2; kkq++) {
      bf16x8 af[4], bfr[4];
      #pragma unroll
      for (int i = 0; i < 4; i++) {
        int row = wm * 64 + i * 16 + l15;
        int ch = (kkq * 4 + g) ^ (row & 7);
        af[i] = *(const bf16x8*)((const char*)As + row * 128 + ch * 16);
      }
      #pragma unroll
      for (int j = 0; j < 4; j++) {
        int row = wn * 64 + j * 16 + l15;
        int ch = (kkq * 4 + g) ^ (row & 7);
        bfr[j] = *(const bf16x8*)((const char*)Bs + row * 128 + ch * 16);
      }
      #pragma unroll
      for (int i = 0; i < 4; i++)
        #pragma unroll
        for (int j = 0; j < 4; j++)
          acc[i][j] = MFMA16(af[i], bfr[j], acc[i][j]);
    }
  }

  if (MODE == 0 && blockIdx.z == 2) {
    // V: write transposed [B,H,64,S]
    #pragma unroll
    for (int i = 0; i < 4; i++)
      #pragma unroll
      for (int j = 0; j < 4; j++) {
        int m0 = blockIdx.y * 128 + wm * 64 + i * 16 + g * 4;
        int n = blockIdx.x * 128 + wn * 64 + j * 16 + l15;
        size_t base = (((size_t)(m0 >> 11) * 16 + (n >> 6)) * 64 + (n & 63)) * 2048 + (m0 & 2047);
        bf16x4 o;
        #pragma unroll
        for (int r = 0; r < 4; r++) o[r] = (__bf16)acc[i][j][r];
        *(bf16x4*)((__bf16*)O + base) = o;
      }
  } else {
    #pragma unroll
    for (int i = 0; i < 4; i++)
      #pragma unroll
      for (int j = 0; j < 4; j++)
        #pragma unroll
        for (int r = 0; r < 4; r++) {
          int m = blockIdx.y * 128 + wm * 64 + i * 16 + g * 4 + r;
          int n = blockIdx.x * 128 + wn * 64 + j * 16 + l15;
          float v = acc[i][j][r];
          if (MODE == 0) {
            size_t idx = (((size_t)(m >> 11) * 16 + (n >> 6)) * 2048 + (m & 2047)) * 64 + (n & 63);
            ((__bf16*)O)[idx] = (__bf16)(v * scale);
          } else {
            ((float*)O)[(size_t)m * 1024 + n] = v;
          }
        }
  }
}

// ---------------- flash attention (S^T formulation, shuffle P-transpose) ----------------
__global__ __launch_bounds__(256, 3) void attn(
    const __bf16* __restrict__ qp, const __bf16* __restrict__ kp,
    const __bf16* __restrict__ vt_, __bf16* __restrict__ aout,
    const uint32_t* __restrict__ bits, const int* __restrict__ flags) {
  int qt = blockIdx.x, bh = blockIdx.y, b = bh >> 4, h = bh & 15;
  int tid = threadIdx.x, lane = tid & 63, w = tid >> 6;
  int g = lane >> 4, l15 = lane & 15;

  __shared__ __align__(16) char smem[32768];
  char* Klds = smem;            // [128 kcol][64 dk] bf16, chunk-swizzled
  char* Vlds = smem + 16384;    // [64 dv][128 kcol] bf16, chunk-swizzled

  const __bf16* Qg = qp + ((size_t)bh * S_ + qt * 128) * 64;
  const __bf16* Kg = kp + (size_t)bh * S_ * 64;
  const __bf16* Vg = vt_ + (size_t)bh * 64 * S_;

  // stage Q into Klds region (swizzled [128][64]) and pull frags to registers
  #pragma unroll
  for (int r = 0; r < 4; r++) {
    int C = r * 256 + tid;
    int row = C >> 3, c = C & 7, c0 = c ^ (row & 7);
    glds16(Qg + row * 64 + c0 * 8, Klds + C * 16);
  }
  __syncthreads();
  bf16x8 qf[2][2];  // B-operand frags: Q[qrow=w*32+i*16+l15][dk=kkq*32+g*8+j]
  #pragma unroll
  for (int i = 0; i < 2; i++)
    #pragma unroll
    for (int kkq = 0; kkq < 2; kkq++) {
      int row = w * 32 + i * 16 + l15;
      int ch = (kkq * 4 + g) ^ (row & 7);
      qf[i][kkq] = *(const bf16x8*)(Klds + row * 128 + ch * 16);
    }
  __syncthreads();

  f32x4 oacc[4][2] = {};  // O^T[vcol=vt*16+g*4+r][qrow local i*16+l15]
  float mst[2] = {-INFINITY, -INFINITY}, lst[2] = {0.f, 0.f};

  int srcA = 2 * (g & 1) * 16 + l15;
  int srcB = srcA + 16;
  bool hi = g >= 2;

  for (int kt = 0; kt < 16; kt++) {
    const __bf16* Ks = Kg + (size_t)kt * 128 * 64;
    #pragma unroll
    for (int r = 0; r < 4; r++) {
      int C = r * 256 + tid;
      int row = C >> 3, c = C & 7, c0 = c ^ (row & 7);
      glds16(Ks + row * 64 + c0 * 8, Klds + C * 16);
    }
    #pragma unroll
    for (int r = 0; r < 4; r++) {
      int C = r * 256 + tid;
      int row = C >> 4, c = C & 15;
      int c0 = (c & 8) | ((c & 7) ^ (row & 7));
      glds16(Vg + (size_t)row * S_ + kt * 128 + c0 * 8, Vlds + C * 16);
    }
    __syncthreads();

    // S^T = K * Q^T : sacc[i][jt] holds S^T[kcol=jt*16+g*4+r][qrow=w*32+i*16+l15]
    f32x4 sacc[2][8] = {};
    #pragma unroll
    for (int jt = 0; jt < 8; jt++) {
      int row = jt * 16 + l15;
      bf16x8 kf0 = *(const bf16x8*)(Klds + row * 128 + ((0 * 4 + g) ^ (row & 7)) * 16);
      bf16x8 kf1 = *(const bf16x8*)(Klds + row * 128 + ((1 * 4 + g) ^ (row & 7)) * 16);
      sacc[0][jt] = MFMA16(kf0, qf[0][0], sacc[0][jt]);
      sacc[0][jt] = MFMA16(kf1, qf[0][1], sacc[0][jt]);
      sacc[1][jt] = MFMA16(kf0, qf[1][0], sacc[1][jt]);
      sacc[1][jt] = MFMA16(kf1, qf[1][1], sacc[1][jt]);
    }

    if (!flags[(b * 16 + qt) * 16 + kt]) {  // exact masking (slow path)
      #pragma unroll
      for (int i = 0; i < 2; i++) {
        int srow = qt * 128 + w * 32 + i * 16 + l15;
        const uint32_t* bw = &bits[((size_t)b * S_ + srow) * 64 + kt * 4];
        uint32_t mw[4] = {bw[0], bw[1], bw[2], bw[3]};
        #pragma unroll
        for (int jt = 0; jt < 8; jt++)
          #pragma unroll
          for (int r = 0; r < 4; r++) {
            int bitpos = (jt & 1) * 16 + g * 4 + r;
            if (!((mw[jt >> 1] >> bitpos) & 1)) sacc[i][jt][r] = NEG_;
          }
      }
    }

    // online softmax per qrow (qrow = (i, l15); kcols spread across quads)
    uint32_t pk01[2][8], pk23[2][8];
    float alpha[2];
    #pragma unroll
    for (int i = 0; i < 2; i++) {
      float mx = -INFINITY;
      #pragma unroll
      for (int jt = 0; jt < 8; jt++)
        #pragma unroll
        for (int r = 0; r < 4; r++) mx = fmaxf(mx, sacc[i][jt][r]);
      mx = fmaxf(mx, __shfl_xor(mx, 16));
      mx = fmaxf(mx, __shfl_xor(mx, 32));
      float mnew = fmaxf(mst[i], mx);
      alpha[i] = __expf(mst[i] - mnew);
      mst[i] = mnew;
      float sum = 0.f;
      #pragma unroll
      for (int jt = 0; jt < 8; jt++) {
        float p0 = __expf(sacc[i][jt][0] - mnew);
        float p1 = __expf(sacc[i][jt][1] - mnew);
        float p2 = __expf(sacc[i][jt][2] - mnew);
        float p3 = __expf(sacc[i][jt][3] - mnew);
        sum += (p0 + p1) + (p2 + p3);
        pk01[i][jt] = pack_bf16(p0, p1);
        pk23[i][jt] = pack_bf16(p2, p3);
      }
      sum += __shfl_xor(sum, 16);
      sum += __shfl_xor(sum, 32);
      lst[i] = lst[i] * alpha[i] + sum;
    }
    #pragma unroll
    for (int vt = 0; vt < 4; vt++)
      #pragma unroll
      for (int i = 0; i < 2; i++)
        #pragma unroll
        for (int r = 0; r < 4; r++) oacc[vt][i][r] *= alpha[i];

    // O^T += V^T * P^T ; P^T b-frags assembled by cross-lane shuffles
    #pragma unroll
    for (int kk = 0; kk < 4; kk++) {
      bf16x8 vf[4];
      #pragma unroll
      for (int vt = 0; vt < 4; vt++) {
        int row = vt * 16 + l15;
        int ch = kk * 4 + g;
        int chs = (ch & 8) | ((ch & 7) ^ (row & 7));
        vf[vt] = *(const bf16x8*)(Vlds + row * 256 + chs * 16);
      }
      #pragma unroll
      for (int i = 0; i < 2; i++) {
        uint32_t d0a = __shfl(pk01[i][kk * 2], srcA), d0b = __shfl(pk01[i][kk * 2 + 1], srcA);
        uint32_t d1a = __shfl(pk23[i][kk * 2], srcA), d1b = __shfl(pk23[i][kk * 2 + 1], srcA);
        uint32_t d2a = __shfl(pk01[i][kk * 2], srcB), d2b = __shfl(pk01[i][kk * 2 + 1], srcB);
        uint32_t d3a = __shfl(pk23[i][kk * 2], srcB), d3b = __shfl(pk23[i][kk * 2 + 1], srcB);
        union { uint32_t u[4]; bf16x8 v; } pf;
        pf.u[0] = hi ? d0b : d0a;
        pf.u[1] = hi ? d1b : d1a;
        pf.u[2] = hi ? d2b : d2a;
        pf.u[3] = hi ? d3b : d3a;
        #pragma unroll
        for (int vt = 0; vt < 4; vt++)
          oacc[vt][i] = MFMA16(vf[vt], pf.v, oacc[vt][i]);
      }
    }
    __syncthreads();
  }

  // epilogue: O^T / l -> attn_out [B,S,H*64] bf16, packed 4-wide stores
  #pragma unroll
  for (int i = 0; i < 2; i++) {
    float inv = 1.0f / lst[i];
    int srow = qt * 128 + w * 32 + i * 16 + l15;
    #pragma unroll
    for (int vt = 0; vt < 4; vt++) {
      bf16x4 o;
      #pragma unroll
      for (int r = 0; r < 4; r++) o[r] = (__bf16)(oacc[vt][i][r] * inv);
      *(bf16x4*)(aout + ((size_t)b * S_ + srow) * 1024 + h * 64 + vt * 16 + g * 4) = o;
    }
  }
}

// ---------------- launch ----------------
extern "C" void kernel_launch(void* const* d_in, const int* in_sizes, int n_in,
                              void* d_out, int out_size, void* d_ws, size_t ws_size,
                              hipStream_t stream) {
  const float* queries = (const float*)d_in[0];
  const float* keys    = (const float*)d_in[1];
  const float* values  = (const float*)d_in[2];
  const int*   mask    = (const int*)d_in[3];
  const float* Wq      = (const float*)d_in[4];
  const float* Wk      = (const float*)d_in[5];
  const float* Wv      = (const float*)d_in[6];
  const float* Wo      = (const float*)d_in[7];

  char* ws = (char*)d_ws;
  __bf16* Xq  = (__bf16*)(ws + 0);          // 16 MB, later reused as attn_out
  __bf16* Xk  = (__bf16*)(ws + 16777216);   // 16 MB
  __bf16* Xv  = (__bf16*)(ws + 33554432);   // 16 MB
  __bf16* Wqb = (__bf16*)(ws + 50331648);   // 2 MB each
  __bf16* Wkb = (__bf16*)(ws + 52428800);
  __bf16* Wvb = (__bf16*)(ws + 54525952);
  __bf16* Wob = (__bf16*)(ws + 56623104);
  __bf16* qp  = (__bf16*)(ws + 58720256);   // 16 MB [B,H,S,64]
  __bf16* kp  = (__bf16*)(ws + 75497472);   // 16 MB [B,H,S,64]
  __bf16* vT  = (__bf16*)(ws + 92274688);   // 16 MB [B,H,64,S]
  uint32_t* bits = (uint32_t*)(ws + 109051904);  // 2 MB
  int* flags     = (int*)(ws + 111149056);       // 4 KB
  __bf16* aout = Xq;  // alias: Xq dead after proj GEMM

  cvt3<<<dim3(8192, 1, 3), 256, 0, stream>>>(queries, keys, values, Xq, Xk, Xv);
  cvt4<<<dim3(1024, 1, 4), 256, 0, stream>>>(Wq, Wk, Wv, Wo, Wqb, Wkb, Wvb, Wob);

  mask_pack<<<dim3(16, 16, 4), 256, 0, stream>>>(mask, bits, flags);

  gemm_bt<0><<<dim3(8, 64, 3), 256, 0, stream>>>(Xq, Xk, Xv, Wqb, Wkb, Wvb,
                                                 (void*)qp, (void*)kp, (void*)vT);

  attn<<<dim3(16, 64), 256, 0, stream>>>(qp, kp, vT, aout, bits, flags);

  gemm_bt<1><<<dim3(8, 64, 1), 256, 0, stream>>>(aout, nullptr, nullptr, Wob, nullptr, nullptr,
                                                 (void*)d_out, nullptr, nullptr);
}

// Round 3
// 438.020 us; speedup vs baseline: 1.2660x; 1.1118x over previous
//
#include <hip/hip_runtime.h>
#include <stdint.h>

typedef __attribute__((ext_vector_type(4))) float f32x4;
typedef __attribute__((ext_vector_type(8))) __bf16 bf16x8;
typedef __attribute__((ext_vector_type(4))) __bf16 bf16x4;
typedef __attribute__((ext_vector_type(4))) short s16x4;
typedef __attribute__((ext_vector_type(2))) uint32_t u32x2;

#define MFMA16(a, b, c) __builtin_amdgcn_mfma_f32_16x16x32_bf16(a, b, c, 0, 0, 0)
#define MFMA16K16(a, b, c) __builtin_amdgcn_mfma_f32_16x16x16bf16_1k(a, b, c, 0, 0, 0)

#define B_ 4
#define S_ 2048
#define D_ 1024
#define H_ 16
#define NEG_ -1e10f

__device__ __forceinline__ void glds16(const void* gsrc, void* ldst) {
  __builtin_amdgcn_global_load_lds(
      (__attribute__((address_space(1))) void*)(gsrc),
      (__attribute__((address_space(3))) void*)(ldst),
      16, 0, 0);
}

__device__ __forceinline__ uint32_t pack_bf16(float a, float b) {
  uint32_t ua = (uint32_t)__builtin_bit_cast(unsigned short, (__bf16)a);
  uint32_t ub = (uint32_t)__builtin_bit_cast(unsigned short, (__bf16)b);
  return ua | (ub << 16);
}

// ---------------- fp32 -> bf16 converts (fused) ----------------
__global__ __launch_bounds__(256) void cvt3(const float* __restrict__ a, const float* __restrict__ b,
                                            const float* __restrict__ c, __bf16* __restrict__ oa,
                                            __bf16* __restrict__ ob, __bf16* __restrict__ oc) {
  const float* in; __bf16* out;
  if (blockIdx.z == 0) { in = a; out = oa; }
  else if (blockIdx.z == 1) { in = b; out = ob; }
  else { in = c; out = oc; }
  int i = (blockIdx.x * 256 + threadIdx.x) * 4;
  float4 v = *(const float4*)(in + i);
  bf16x4 o;
  o.x = (__bf16)v.x; o.y = (__bf16)v.y; o.z = (__bf16)v.z; o.w = (__bf16)v.w;
  *(bf16x4*)(out + i) = o;
}

__global__ __launch_bounds__(256) void cvt4(const float* __restrict__ a, const float* __restrict__ b,
                                            const float* __restrict__ c, const float* __restrict__ d,
                                            __bf16* __restrict__ oa, __bf16* __restrict__ ob,
                                            __bf16* __restrict__ oc, __bf16* __restrict__ od) {
  const float* in; __bf16* out;
  if (blockIdx.z == 0) { in = a; out = oa; }
  else if (blockIdx.z == 1) { in = b; out = ob; }
  else if (blockIdx.z == 2) { in = c; out = oc; }
  else { in = d; out = od; }
  int i = (blockIdx.x * 256 + threadIdx.x) * 4;
  float4 v = *(const float4*)(in + i);
  bf16x4 o;
  o.x = (__bf16)v.x; o.y = (__bf16)v.y; o.z = (__bf16)v.z; o.w = (__bf16)v.w;
  *(bf16x4*)(out + i) = o;
}

// ---------------- mask pack: bits + per-tile all-ones flags ----------------
__global__ __launch_bounds__(256) void mask_pack(const int* __restrict__ mask,
                                                 uint32_t* __restrict__ bits,
                                                 int* __restrict__ flags) {
  int tt = blockIdx.x, st = blockIdx.y, b = blockIdx.z;
  int tid = threadIdx.x, w = tid >> 6, lane = tid & 63;
  __shared__ int andred;
  if (tid == 0) andred = 1;
  __syncthreads();
  unsigned long long all1 = ~0ull;
  for (int rr = 0; rr < 32; rr++) {
    int srow = st * 128 + w * 32 + rr;
    #pragma unroll
    for (int half = 0; half < 2; half++) {
      int c = tt * 128 + half * 64 + lane;
      int m = mask[((size_t)b * S_ + srow) * S_ + c];
      unsigned long long bal = __ballot(m != 0);
      all1 &= bal;
      if (lane == 0) {
        uint32_t* dst = &bits[((size_t)b * S_ + srow) * 64 + tt * 4 + half * 2];
        dst[0] = (uint32_t)bal;
        dst[1] = (uint32_t)(bal >> 32);
      }
    }
  }
  if (all1 != ~0ull) atomicAnd(&andred, 0);
  __syncthreads();
  if (tid == 0) flags[(b * 16 + st) * 16 + tt] = andred;
}

// ---------------- GEMM: acc[i][j] = dot(PA_row, PB_row), K=1024, BK=64 swizzled ----------------
// MODE 0: z=0 q: PA=Wq PB=Xq -> qp [B,H,S,64] *0.125 ; z=1 k likewise -> kp ;
//         z=2 v: PA=Xv PB=Wv -> vT [B,H,64,S]. All packed bf16x4 stores.
// MODE 1: PA=aout PB=Wo -> f32 out row-major [M,1024]
template <int MODE>
__global__ __launch_bounds__(256, 2) void gemm_bt(
    const __bf16* __restrict__ A0, const __bf16* __restrict__ A1, const __bf16* __restrict__ A2,
    const __bf16* __restrict__ W0, const __bf16* __restrict__ W1, const __bf16* __restrict__ W2,
    void* O0, void* O1, void* O2) {
  const int K = 1024;
  const __bf16* PA; const __bf16* PB; void* O;
  int pa_t, pb_t;
  if (MODE == 0) {
    if (blockIdx.z == 0)      { PA = W0; PB = A0; O = O0; pa_t = blockIdx.x; pb_t = blockIdx.y; }
    else if (blockIdx.z == 1) { PA = W1; PB = A1; O = O1; pa_t = blockIdx.x; pb_t = blockIdx.y; }
    else                      { PA = A2; PB = W2; O = O2; pa_t = blockIdx.y; pb_t = blockIdx.x; }
  } else { PA = A0; PB = W0; O = O0; pa_t = blockIdx.y; pb_t = blockIdx.x; }

  __shared__ __align__(16) __bf16 As[128 * 64];
  __shared__ __align__(16) __bf16 Bs[128 * 64];
  int tid = threadIdx.x, lane = tid & 63, w = tid >> 6;
  int wm = w >> 1, wn = w & 1;
  int g = lane >> 4, l15 = lane & 15;
  f32x4 acc[4][4] = {};
  const __bf16* Ablk = PA + (size_t)(pa_t * 128) * K;
  const __bf16* Bblk = PB + (size_t)(pb_t * 128) * K;

  for (int kt = 0; kt < K; kt += 64) {
    __syncthreads();
    #pragma unroll
    for (int r = 0; r < 4; r++) {
      int C = r * 256 + tid;
      int row = C >> 3, c = C & 7;
      int c0 = c ^ (row & 7);
      glds16(Ablk + (size_t)row * K + kt + c0 * 8, (char*)As + C * 16);
      glds16(Bblk + (size_t)row * K + kt + c0 * 8, (char*)Bs + C * 16);
    }
    __syncthreads();
    #pragma unroll
    for (int kkq = 0; kkq < 2; kkq++) {
      bf16x8 af[4], bfr[4];
      #pragma unroll
      for (int i = 0; i < 4; i++) {
        int row = wm * 64 + i * 16 + l15;
        int ch = (kkq * 4 + g) ^ (row & 7);
        af[i] = *(const bf16x8*)((const char*)As + row * 128 + ch * 16);
      }
      #pragma unroll
      for (int j = 0; j < 4; j++) {
        int row = wn * 64 + j * 16 + l15;
        int ch = (kkq * 4 + g) ^ (row & 7);
        bfr[j] = *(const bf16x8*)((const char*)Bs + row * 128 + ch * 16);
      }
      #pragma unroll
      for (int i = 0; i < 4; i++)
        #pragma unroll
        for (int j = 0; j < 4; j++)
          acc[i][j] = MFMA16(af[i], bfr[j], acc[i][j]);
    }
  }

  if (MODE == 1) {
    #pragma unroll
    for (int i = 0; i < 4; i++)
      #pragma unroll
      for (int j = 0; j < 4; j++)
        #pragma unroll
        for (int r = 0; r < 4; r++) {
          int m = pa_t * 128 + wm * 64 + i * 16 + g * 4 + r;
          int n = pb_t * 128 + wn * 64 + j * 16 + l15;
          ((float*)O)[(size_t)m * 1024 + n] = acc[i][j][r];
        }
  } else if (blockIdx.z == 2) {
    // v -> vT [B,H,64,S]; rows of PA are s, rows of PB are dv
    #pragma unroll
    for (int i = 0; i < 4; i++)
      #pragma unroll
      for (int j = 0; j < 4; j++) {
        int s0 = pa_t * 128 + wm * 64 + i * 16 + g * 4;
        int dvg = pb_t * 128 + wn * 64 + j * 16 + l15;
        int b = s0 >> 11, s = s0 & 2047;
        int h = dvg >> 6, dv = dvg & 63;
        bf16x4 o;
        #pragma unroll
        for (int r = 0; r < 4; r++) o[r] = (__bf16)acc[i][j][r];
        *(bf16x4*)((__bf16*)O + (((size_t)b * 16 + h) * 64 + dv) * 2048 + s) = o;
      }
  } else {
    // q/k -> [B,H,S,64]; rows of PA are dk, rows of PB are s
    float scale = (blockIdx.z == 0) ? 0.125f : 1.0f;
    #pragma unroll
    for (int i = 0; i < 4; i++)
      #pragma unroll
      for (int j = 0; j < 4; j++) {
        int dkg = pa_t * 128 + wm * 64 + i * 16 + g * 4;
        int sg = pb_t * 128 + wn * 64 + j * 16 + l15;
        int h = dkg >> 6, dk = dkg & 63;
        int b = sg >> 11, s = sg & 2047;
        bf16x4 o;
        #pragma unroll
        for (int r = 0; r < 4; r++) o[r] = (__bf16)(acc[i][j][r] * scale);
        *(bf16x4*)((__bf16*)O + (((size_t)b * 16 + h) * 2048 + s) * 64 + dk) = o;
      }
  }
}

// ---------------- flash attention (S^T formulation, K=16 MFMA for PV: no transpose) ----------------
__global__ __launch_bounds__(256, 3) void attn(
    const __bf16* __restrict__ qp, const __bf16* __restrict__ kp,
    const __bf16* __restrict__ vt_, __bf16* __restrict__ aout,
    const uint32_t* __restrict__ bits, const int* __restrict__ flags) {
  int qt = blockIdx.x, bh = blockIdx.y, b = bh >> 4, h = bh & 15;
  int tid = threadIdx.x, lane = tid & 63, w = tid >> 6;
  int g = lane >> 4, l15 = lane & 15;

  __shared__ __align__(16) char smem[32768];
  char* Klds = smem;            // [128 kcol][64 dk] bf16, chunk-swizzled
  char* Vlds = smem + 16384;    // [64 dv][128 kcol] bf16, chunk-swizzled

  const __bf16* Qg = qp + ((size_t)bh * S_ + qt * 128) * 64;
  const __bf16* Kg = kp + (size_t)bh * S_ * 64;
  const __bf16* Vg = vt_ + (size_t)bh * 64 * S_;

  // stage Q (swizzled [128][64]) into Klds region, pull B-operand frags
  #pragma unroll
  for (int r = 0; r < 4; r++) {
    int C = r * 256 + tid;
    int row = C >> 3, c = C & 7, c0 = c ^ (row & 7);
    glds16(Qg + row * 64 + c0 * 8, Klds + C * 16);
  }
  __syncthreads();
  bf16x8 qf[2][2];  // Q[qrow=w*32+i*16+l15][dk=kkq*32+g*8+j]
  #pragma unroll
  for (int i = 0; i < 2; i++)
    #pragma unroll
    for (int kkq = 0; kkq < 2; kkq++) {
      int row = w * 32 + i * 16 + l15;
      int ch = (kkq * 4 + g) ^ (row & 7);
      qf[i][kkq] = *(const bf16x8*)(Klds + row * 128 + ch * 16);
    }
  __syncthreads();

  f32x4 oacc[4][2] = {};  // O^T[dv=vt*16+g*4+r][qrow=w*32+i*16+l15]
  float mst[2] = {-INFINITY, -INFINITY}, lst[2] = {0.f, 0.f};

  for (int kt = 0; kt < 16; kt++) {
    const __bf16* Ks = Kg + (size_t)kt * 128 * 64;
    #pragma unroll
    for (int r = 0; r < 4; r++) {
      int C = r * 256 + tid;
      int row = C >> 3, c = C & 7, c0 = c ^ (row & 7);
      glds16(Ks + row * 64 + c0 * 8, Klds + C * 16);
    }
    #pragma unroll
    for (int r = 0; r < 4; r++) {
      int C = r * 256 + tid;
      int row = C >> 4, c = C & 15;
      int c0 = (c & 8) | ((c & 7) ^ (row & 7));
      glds16(Vg + (size_t)row * S_ + kt * 128 + c0 * 8, Vlds + C * 16);
    }
    __syncthreads();

    int flag = flags[(b * 16 + qt) * 16 + kt];

    #pragma unroll
    for (int hh = 0; hh < 2; hh++) {  // 64-kcol halves: halves register pressure
      // S^T = K * Q^T ; sacc[i][jt]: kcol=(hh*4+jt)*16+g*4+r, qrow=w*32+i*16+l15
      f32x4 sacc[2][4] = {};
      #pragma unroll
      for (int jt = 0; jt < 4; jt++) {
        int row = (hh * 4 + jt) * 16 + l15;
        bf16x8 kf0 = *(const bf16x8*)(Klds + row * 128 + (g ^ (row & 7)) * 16);
        bf16x8 kf1 = *(const bf16x8*)(Klds + row * 128 + ((4 + g) ^ (row & 7)) * 16);
        sacc[0][jt] = MFMA16(kf0, qf[0][0], sacc[0][jt]);
        sacc[0][jt] = MFMA16(kf1, qf[0][1], sacc[0][jt]);
        sacc[1][jt] = MFMA16(kf0, qf[1][0], sacc[1][jt]);
        sacc[1][jt] = MFMA16(kf1, qf[1][1], sacc[1][jt]);
      }

      if (!flag) {  // exact masking slow path
        #pragma unroll
        for (int i = 0; i < 2; i++) {
          int srow = qt * 128 + w * 32 + i * 16 + l15;
          const uint32_t* bw = &bits[((size_t)b * S_ + srow) * 64 + kt * 4 + hh * 2];
          uint32_t m0 = bw[0], m1 = bw[1];
          #pragma unroll
          for (int jt = 0; jt < 4; jt++) {
            uint32_t mw = (jt & 2) ? m1 : m0;
            #pragma unroll
            for (int r = 0; r < 4; r++) {
              int bitpos = (jt & 1) * 16 + g * 4 + r;
              if (!((mw >> bitpos) & 1)) sacc[i][jt][r] = NEG_;
            }
          }
        }
      }

      // online softmax per qrow; pack P directly into 16x16x16 B-operand layout
      s16x4 pf[2][4];
      float alpha[2];
      #pragma unroll
      for (int i = 0; i < 2; i++) {
        float mx = -INFINITY;
        #pragma unroll
        for (int jt = 0; jt < 4; jt++)
          #pragma unroll
          for (int r = 0; r < 4; r++) mx = fmaxf(mx, sacc[i][jt][r]);
        mx = fmaxf(mx, __shfl_xor(mx, 16));
        mx = fmaxf(mx, __shfl_xor(mx, 32));
        float mnew = fmaxf(mst[i], mx);
        alpha[i] = __expf(mst[i] - mnew);
        mst[i] = mnew;
        float sum = 0.f;
        #pragma unroll
        for (int jt = 0; jt < 4; jt++) {
          float p0 = __expf(sacc[i][jt][0] - mnew);
          float p1 = __expf(sacc[i][jt][1] - mnew);
          float p2 = __expf(sacc[i][jt][2] - mnew);
          float p3 = __expf(sacc[i][jt][3] - mnew);
          sum += (p0 + p1) + (p2 + p3);
          u32x2 t;
          t.x = pack_bf16(p0, p1);
          t.y = pack_bf16(p2, p3);
          pf[i][jt] = __builtin_bit_cast(s16x4, t);
        }
        sum += __shfl_xor(sum, 16);
        sum += __shfl_xor(sum, 32);
        lst[i] = lst[i] * alpha[i] + sum;
      }
      #pragma unroll
      for (int vt = 0; vt < 4; vt++)
        #pragma unroll
        for (int i = 0; i < 2; i++)
          #pragma unroll
          for (int r = 0; r < 4; r++) oacc[vt][i][r] *= alpha[i];

      // O^T += V^T * P^T via 16x16x16 MFMA (P already in B-operand layout)
      #pragma unroll
      for (int jt = 0; jt < 4; jt++) {
        int ch = (hh * 4 + jt) * 2 + (g >> 1);
        #pragma unroll
        for (int vt = 0; vt < 4; vt++) {
          int row = vt * 16 + l15;
          int chs = (ch & 8) | ((ch & 7) ^ (row & 7));
          s16x4 vv = *(const s16x4*)(Vlds + row * 256 + chs * 16 + (g & 1) * 8);
          oacc[vt][0] = MFMA16K16(vv, pf[0][jt], oacc[vt][0]);
          oacc[vt][1] = MFMA16K16(vv, pf[1][jt], oacc[vt][1]);
        }
      }
    }
    __syncthreads();
  }

  // epilogue: O^T / l -> attn_out [B,S,H*64] bf16
  #pragma unroll
  for (int i = 0; i < 2; i++) {
    float inv = 1.0f / lst[i];
    int srow = qt * 128 + w * 32 + i * 16 + l15;
    #pragma unroll
    for (int vt = 0; vt < 4; vt++) {
      bf16x4 o;
      #pragma unroll
      for (int r = 0; r < 4; r++) o[r] = (__bf16)(oacc[vt][i][r] * inv);
      *(bf16x4*)(aout + ((size_t)b * S_ + srow) * 1024 + h * 64 + vt * 16 + g * 4) = o;
    }
  }
}

// ---------------- launch ----------------
extern "C" void kernel_launch(void* const* d_in, const int* in_sizes, int n_in,
                              void* d_out, int out_size, void* d_ws, size_t ws_size,
                              hipStream_t stream) {
  const float* queries = (const float*)d_in[0];
  const float* keys    = (const float*)d_in[1];
  const float* values  = (const float*)d_in[2];
  const int*   mask    = (const int*)d_in[3];
  const float* Wq      = (const float*)d_in[4];
  const float* Wk      = (const float*)d_in[5];
  const float* Wv      = (const float*)d_in[6];
  const float* Wo      = (const float*)d_in[7];

  char* ws = (char*)d_ws;
  __bf16* Xq  = (__bf16*)(ws + 0);          // 16 MB, later reused as attn_out
  __bf16* Xk  = (__bf16*)(ws + 16777216);   // 16 MB
  __bf16* Xv  = (__bf16*)(ws + 33554432);   // 16 MB
  __bf16* Wqb = (__bf16*)(ws + 50331648);   // 2 MB each
  __bf16* Wkb = (__bf16*)(ws + 52428800);
  __bf16* Wvb = (__bf16*)(ws + 54525952);
  __bf16* Wob = (__bf16*)(ws + 56623104);
  __bf16* qp  = (__bf16*)(ws + 58720256);   // 16 MB [B,H,S,64]
  __bf16* kp  = (__bf16*)(ws + 75497472);   // 16 MB [B,H,S,64]
  __bf16* vT  = (__bf16*)(ws + 92274688);   // 16 MB [B,H,64,S]
  uint32_t* bits = (uint32_t*)(ws + 109051904);  // 2 MB
  int* flags     = (int*)(ws + 111149056);       // 4 KB
  __bf16* aout = Xq;  // alias: Xq dead after proj GEMM

  cvt3<<<dim3(8192, 1, 3), 256, 0, stream>>>(queries, keys, values, Xq, Xk, Xv);
  cvt4<<<dim3(1024, 1, 4), 256, 0, stream>>>(Wq, Wk, Wv, Wo, Wqb, Wkb, Wvb, Wob);

  mask_pack<<<dim3(16, 16, 4), 256, 0, stream>>>(mask, bits, flags);

  gemm_bt<0><<<dim3(8, 64, 3), 256, 0, stream>>>(Xq, Xk, Xv, Wqb, Wkb, Wvb,
                                                 (void*)qp, (void*)kp, (void*)vT);

  attn<<<dim3(16, 64), 256, 0, stream>>>(qp, kp, vT, aout, bits, flags);

  gemm_bt<1><<<dim3(8, 64, 1), 256, 0, stream>>>(aout, nullptr, nullptr, Wob, nullptr, nullptr,
                                                 (void*)d_out, nullptr, nullptr);
}